// Round 5
// baseline (46.762 us; speedup 1.0000x reference)
//
#include <hip/hip_runtime.h>
#include <math.h>

// VectorQuantizer: B=4, T=2048, DIM=64, NUM_CODES=512
// out = [ k as float (8192) | z_q (8192*64) ]
//
// R4: FUSED single kernel, no LDS staging (operands straight from L1/L2),
// no workspace. Block = 256 thr (4 waves) = 16 queries; wave w owns the
// 128-code quarter [w*128, w*128+128); lane tile 4q x 4c; per-lane 2 chunks
// of 4 codes. Distance math bit-matches the validated R0/R3 path:
// acc[d&7] ascending-dim accumulation, fixed combine tree, IEEE sqrtf,
// strict-< ascending-index argmin, lexicographic cross-lane/wave reduce.

#define NQ      8192
#define VDIM    64
#define NCODES  512

__global__ __launch_bounds__(256, 2) void vq_fused_kernel(
    const float* __restrict__ inp,     // [NQ][VDIM]
    const float* __restrict__ table,   // [NCODES][VDIM]
    float* __restrict__ out)           // [NQ + NQ*VDIM]
{
    __shared__ float red_n[4][16];
    __shared__ int   red_i[4][16];
    __shared__ int   kidx[16];

    const int tid  = threadIdx.x;
    const int wave = tid >> 6;          // 0..3 -> code quarter
    const int lane = tid & 63;
    const int qg   = lane >> 4;         // 0..3: queries qg*4..+3 (of block's 16)
    const int cg   = lane & 15;         // 0..15: codes cg*4..+3 (of 64-chunk)

    const int qbase = blockIdx.x * 16;  // 512 blocks x 16 queries
    const float* qrow = inp + (size_t)(qbase + qg * 4) * VDIM;   // 4 query rows

    float bd[4];
    int   bi[4];
#pragma unroll
    for (int i = 0; i < 4; ++i) { bd[i] = INFINITY; bi[i] = 0; }

#pragma clang loop unroll(disable)
    for (int chunk = 0; chunk < 2; ++chunk) {
        const int cbase = wave * 128 + chunk * 64 + cg * 4;      // lane's 4 codes
        const float* crow = table + (size_t)cbase * VDIM;

        float acc[4][4][8];
#pragma unroll
        for (int i = 0; i < 4; ++i)
#pragma unroll
            for (int j = 0; j < 4; ++j)
#pragma unroll
                for (int m = 0; m < 8; ++m) acc[i][j][m] = 0.0f;

#pragma clang loop unroll(disable)
        for (int k = 0; k < 8; ++k) {
            // ---- even half: kc = 2k, dims 8k..8k+3 -> acc[0..3] ----
            {
                const int kc = 2 * k;
                float4 qv[4], cv[4];
#pragma unroll
                for (int i = 0; i < 4; ++i)
                    qv[i] = *reinterpret_cast<const float4*>(qrow + i * VDIM + kc * 4);
#pragma unroll
                for (int j = 0; j < 4; ++j)
                    cv[j] = *reinterpret_cast<const float4*>(crow + j * VDIM + kc * 4);
#pragma unroll
                for (int i = 0; i < 4; ++i)
#pragma unroll
                    for (int j = 0; j < 4; ++j) {
                        float d0 = qv[i].x - cv[j].x;
                        float d1 = qv[i].y - cv[j].y;
                        float d2 = qv[i].z - cv[j].z;
                        float d3 = qv[i].w - cv[j].w;
                        acc[i][j][0] = __builtin_fmaf(d0, d0, acc[i][j][0]);
                        acc[i][j][1] = __builtin_fmaf(d1, d1, acc[i][j][1]);
                        acc[i][j][2] = __builtin_fmaf(d2, d2, acc[i][j][2]);
                        acc[i][j][3] = __builtin_fmaf(d3, d3, acc[i][j][3]);
                    }
            }
            // ---- odd half: kc = 2k+1, dims 8k+4..8k+7 -> acc[4..7] ----
            {
                const int kc = 2 * k + 1;
                float4 qv[4], cv[4];
#pragma unroll
                for (int i = 0; i < 4; ++i)
                    qv[i] = *reinterpret_cast<const float4*>(qrow + i * VDIM + kc * 4);
#pragma unroll
                for (int j = 0; j < 4; ++j)
                    cv[j] = *reinterpret_cast<const float4*>(crow + j * VDIM + kc * 4);
#pragma unroll
                for (int i = 0; i < 4; ++i)
#pragma unroll
                    for (int j = 0; j < 4; ++j) {
                        float d0 = qv[i].x - cv[j].x;
                        float d1 = qv[i].y - cv[j].y;
                        float d2 = qv[i].z - cv[j].z;
                        float d3 = qv[i].w - cv[j].w;
                        acc[i][j][4] = __builtin_fmaf(d0, d0, acc[i][j][4]);
                        acc[i][j][5] = __builtin_fmaf(d1, d1, acc[i][j][5]);
                        acc[i][j][6] = __builtin_fmaf(d2, d2, acc[i][j][6]);
                        acc[i][j][7] = __builtin_fmaf(d3, d3, acc[i][j][7]);
                    }
            }
        }

        // ---- Combine tree (exact), sqrt, argmin over this chunk's 4 codes ----
#pragma unroll
        for (int j = 0; j < 4; ++j) {          // ascending code index
#pragma unroll
            for (int i = 0; i < 4; ++i) {
                float s = ((acc[i][j][0] + acc[i][j][1]) + (acc[i][j][2] + acc[i][j][3]))
                        + ((acc[i][j][4] + acc[i][j][5]) + (acc[i][j][6] + acc[i][j][7]));
                float n = sqrtf(s);
                if (n < bd[i]) { bd[i] = n; bi[i] = cbase + j; }
            }
        }
    }

    // ---- Reduce across the 16 code-groups (within each 16-lane qg group) ----
#pragma unroll
    for (int off = 1; off < 16; off <<= 1) {
#pragma unroll
        for (int i = 0; i < 4; ++i) {
            float nd = __shfl_xor(bd[i], off, 64);
            int   ni = __shfl_xor(bi[i], off, 64);
            if (nd < bd[i] || (nd == bd[i] && ni < bi[i])) { bd[i] = nd; bi[i] = ni; }
        }
    }

    // ---- Cross-wave reduce via LDS (waves = ascending code quarters) ----
    if (cg == 0) {
#pragma unroll
        for (int i = 0; i < 4; ++i) {
            red_n[wave][qg * 4 + i] = bd[i];
            red_i[wave][qg * 4 + i] = bi[i];
        }
    }
    __syncthreads();

    if (tid < 16) {
        float best = INFINITY;
        int   bidx = 0;
#pragma unroll
        for (int w = 0; w < 4; ++w) {          // ascending code ranges
            float n = red_n[w][tid];
            int   i = red_i[w][tid];
            if (n < best || (n == best && i < bidx)) { best = n; bidx = i; }
        }
        kidx[tid] = bidx;
        out[qbase + tid] = (float)bidx;        // k as float
    }
    __syncthreads();

    // ---- Gather z_q: 16 q x 64 d = 1024 floats, coalesced ----
#pragma unroll
    for (int it = 0; it < 4; ++it) {
        int flat = it * 256 + tid;             // 0..1023
        int ql = flat >> 6;
        int d  = flat & 63;
        int bidx = kidx[ql];
        out[NQ + (size_t)(qbase + ql) * VDIM + d] = table[(size_t)bidx * VDIM + d];
    }
}

extern "C" void kernel_launch(void* const* d_in, const int* in_sizes, int n_in,
                              void* d_out, int out_size, void* d_ws, size_t ws_size,
                              hipStream_t stream) {
    const float* inp   = (const float*)d_in[0];   // [4,2048,64] fp32
    const float* table = (const float*)d_in[1];   // [512,64]    fp32
    float* out = (float*)d_out;

    vq_fused_kernel<<<dim3(NQ / 16), dim3(256), 0, stream>>>(inp, table, out);
}